// Round 1
// baseline (1333.242 us; speedup 1.0000x reference)
//
#include <hip/hip_runtime.h>
#include <math.h>

// FourierButterworthHFCFilter: median-fill -> Butterworth HFC (FFT2) -> percentile norm
// B=16, C=3, H=W=512. 48 channels of 262144 fp32.

#define HN 512
#define WN 512
#define NPIX (HN * WN)   // 262144
#define NCH 48
#define MED_K 131071u    // (n-1)//2

typedef unsigned int u32;

// ---------------- helpers ----------------

__device__ __forceinline__ int rev9(int e) {
  return (int)(__brev((unsigned)e) >> 23);
}

// monotonic float->uint key (no NaNs in input)
__device__ __forceinline__ u32 f2key(float f) {
  u32 u = __float_as_uint(f);
  return u ^ ((u & 0x80000000u) ? 0xFFFFFFFFu : 0x80000000u);
}
__device__ __forceinline__ float key2f(u32 k) {
  u32 u = (k & 0x80000000u) ? (k ^ 0x80000000u) : ~k;
  return __uint_as_float(u);
}

// cooperative 65536-bin scan helpers (256 threads, 256 bins/thread)
__device__ void chunk_sums(const u32* __restrict__ h, u32* csum, u32* cpre) {
  int t = threadIdx.x;
  u32 s = 0;
  for (int i = 0; i < 256; ++i) s += h[(t << 8) + i];
  csum[t] = s;
  __syncthreads();
  if (t == 0) {
    u32 a = 0;
    for (int i = 0; i < 256; ++i) { cpre[i] = a; a += csum[i]; }
  }
  __syncthreads();
}

// find bin containing rank r (0-based). Only owning thread writes outputs.
__device__ void find_rank(const u32* __restrict__ h, const u32* csum, const u32* cpre,
                          u32 r, u32* out_bin, u32* out_pref) {
  int t = threadIdx.x;
  if (cpre[t] <= r && r < cpre[t] + csum[t]) {
    u32 acc = cpre[t];
    for (int i = 0; i < 256; ++i) {
      u32 c = h[(t << 8) + i];
      if (r < acc + c) { *out_bin = (u32)((t << 8) + i); *out_pref = acc; return; }
      acc += c;
    }
  }
}

// ---------------- median (2-pass radix select) ----------------

__global__ __launch_bounds__(256) void khist_hi(const float* __restrict__ x, u32* __restrict__ hist) {
  int ch = blockIdx.x >> 4, bic = blockIdx.x & 15;
  const float* xp = x + (size_t)ch * NPIX + (size_t)bic * (NPIX / 16);
  u32* h = hist + (size_t)ch * 65536;
  for (int i = threadIdx.x; i < NPIX / 16; i += 256) {
    u32 key = f2key(xp[i]);
    atomicAdd(&h[key >> 16], 1u);
  }
}

__global__ __launch_bounds__(256) void kscan_hi(const u32* __restrict__ hist, u32* selhi, u32* pref) {
  int ch = blockIdx.x;
  const u32* h = hist + (size_t)ch * 65536;
  __shared__ u32 csum[256], cpre[256];
  chunk_sums(h, csum, cpre);
  find_rank(h, csum, cpre, MED_K, &selhi[ch], &pref[ch]);
}

__global__ __launch_bounds__(256) void khist_lo(const float* __restrict__ x, u32* __restrict__ hist,
                                                const u32* __restrict__ selhi) {
  int ch = blockIdx.x >> 4, bic = blockIdx.x & 15;
  u32 sh = selhi[ch];
  const float* xp = x + (size_t)ch * NPIX + (size_t)bic * (NPIX / 16);
  u32* h = hist + (size_t)ch * 65536;
  for (int i = threadIdx.x; i < NPIX / 16; i += 256) {
    u32 key = f2key(xp[i]);
    if ((key >> 16) == sh) atomicAdd(&h[key & 0xFFFFu], 1u);
  }
}

__global__ __launch_bounds__(256) void kscan_lo(const u32* __restrict__ hist, const u32* __restrict__ selhi,
                                                const u32* __restrict__ pref, float* med) {
  int ch = blockIdx.x;
  const u32* h = hist + (size_t)ch * 65536;
  __shared__ u32 csum[256], cpre[256];
  __shared__ u32 bin, dummy;
  chunk_sums(h, csum, cpre);
  find_rank(h, csum, cpre, MED_K - pref[ch], &bin, &dummy);
  __syncthreads();
  if (threadIdx.x == 0) {
    u32 key = (selhi[ch] << 16) | bin;
    med[ch] = key2f(key) + 0.2f;   // median_padding adds 0.2
  }
}

// ---------------- 512-pt radix-2 DIT FFT (LDS) ----------------

__device__ __forceinline__ void fft512(float2* a, int t, float sign) {
  #pragma unroll
  for (int ls = 1; ls <= 9; ++ls) {
    const int len = 1 << ls, half = len >> 1;
    int p = t & (half - 1);
    int g = t >> (ls - 1);
    int i0 = (g << ls) | p;
    int i1 = i0 + half;
    float ang = sign * 6.283185307179586f * (float)p / (float)len;
    float sn, cs; __sincosf(ang, &sn, &cs);
    float2 u = a[i0], v = a[i1];
    float2 vw = make_float2(v.x * cs - v.y * sn, v.x * sn + v.y * cs);
    a[i0] = make_float2(u.x + vw.x, u.y + vw.y);
    a[i1] = make_float2(u.x - vw.x, u.y - vw.y);
    __syncthreads();
  }
}

// forward row FFT; builds xp = mask*x + (1-mask)*med on the fly
__global__ __launch_bounds__(256) void kfft_row_fwd(
    const float* __restrict__ x, const float* __restrict__ mask,
    const float* __restrict__ med, float2* __restrict__ cbuf, int ch0) {
  int lch = blockIdx.x >> 9;
  int row = blockIdx.x & 511;
  int gch = ch0 + lch;
  __shared__ float2 lds[512];
  int t = threadIdx.x;
  float m = med[gch];
  size_t gb = (size_t)gch * NPIX + (size_t)row * WN;
  #pragma unroll
  for (int k = 0; k < 2; ++k) {
    int e = t + k * 256;
    float xv = x[gb + e];
    float mv = mask[gb + e];
    float v = mv * xv + (1.0f - mv) * m;
    lds[rev9(e)] = make_float2(v, 0.0f);
  }
  __syncthreads();
  fft512(lds, t, -1.0f);
  size_t cb = (size_t)lch * NPIX + (size_t)row * WN;
  #pragma unroll
  for (int k = 0; k < 2; ++k) {
    int e = t + k * 256;
    cbuf[cb + e] = lds[e];
  }
}

// inverse row FFT + complex magnitude -> out (hfc)
__global__ __launch_bounds__(256) void kfft_row_inv(
    const float2* __restrict__ cbuf, float* __restrict__ out, int ch0) {
  int lch = blockIdx.x >> 9;
  int row = blockIdx.x & 511;
  __shared__ float2 lds[512];
  int t = threadIdx.x;
  size_t cb = (size_t)lch * NPIX + (size_t)row * WN;
  #pragma unroll
  for (int k = 0; k < 2; ++k) {
    int e = t + k * 256;
    lds[rev9(e)] = cbuf[cb + e];
  }
  __syncthreads();
  fft512(lds, t, 1.0f);
  size_t ob = (size_t)(ch0 + lch) * NPIX + (size_t)row * WN;
  #pragma unroll
  for (int k = 0; k < 2; ++k) {
    int e = t + k * 256;
    float2 v = lds[e];
    out[ob + e] = sqrtf(v.x * v.x + v.y * v.y);
  }
}

// column FFT, 8 columns per block. FWD=1: forward + filter*(1/N^2). FWD=0: inverse.
template <int FWD>
__global__ __launch_bounds__(256) void kfft_col(float2* __restrict__ cbuf,
                                                const float* __restrict__ fmap) {
  int lch = blockIdx.x >> 6;
  int c0 = (blockIdx.x & 63) << 3;
  __shared__ float2 lds[8][512];
  int t = threadIdx.x;
  size_t base = (size_t)lch * NPIX;
  #pragma unroll
  for (int i = 0; i < 16; ++i) {
    int idx = (i << 8) + t;
    int h = idx >> 3, c = idx & 7;
    lds[c][rev9(h)] = cbuf[base + (size_t)h * WN + c0 + c];
  }
  __syncthreads();
  const float sign = FWD ? -1.0f : 1.0f;
  #pragma unroll
  for (int ls = 1; ls <= 9; ++ls) {
    const int len = 1 << ls, half = len >> 1;
    int p = t & (half - 1);
    int g = t >> (ls - 1);
    int i0 = (g << ls) | p;
    int i1 = i0 + half;
    float ang = sign * 6.283185307179586f * (float)p / (float)len;
    float sn, cs; __sincosf(ang, &sn, &cs);
    #pragma unroll
    for (int c = 0; c < 8; ++c) {
      float2 u = lds[c][i0], v = lds[c][i1];
      float2 vw = make_float2(v.x * cs - v.y * sn, v.x * sn + v.y * cs);
      lds[c][i0] = make_float2(u.x + vw.x, u.y + vw.y);
      lds[c][i1] = make_float2(u.x - vw.x, u.y - vw.y);
    }
    __syncthreads();
  }
  #pragma unroll
  for (int i = 0; i < 16; ++i) {
    int idx = (i << 8) + t;
    int h = idx >> 3, c = idx & 7;
    float2 v = lds[c][h];
    if (FWD) {
      float f = fmap[h * WN + c0 + c] * (1.0f / (float)NPIX);  // fold 1/N^2 of ifft2
      v.x *= f; v.y *= f;
    }
    cbuf[base + (size_t)h * WN + c0 + c] = v;
  }
}

// ---------------- percentile (exact: temp is quantized to k/256) ----------------

__global__ __launch_bounds__(256) void khist_pct(const float* __restrict__ hfc, u32* __restrict__ hist) {
  int ch = blockIdx.x >> 4, bic = blockIdx.x & 15;
  const float* p = hfc + (size_t)ch * NPIX + (size_t)bic * (NPIX / 16);
  u32* h = hist + (size_t)ch * 65536;
  for (int i = threadIdx.x; i < NPIX / 16; i += 256) {
    float v = fminf(p[i] * 256.0f, 65535.0f);  // hfc >= 0; trunc == floor
    atomicAdd(&h[(u32)v], 1u);
  }
}

__global__ __launch_bounds__(256) void kpct_scan(const u32* __restrict__ hist,
                                                 float* lov, float* invv) {
  int ch = blockIdx.x;
  const u32* h = hist + (size_t)ch * 65536;
  __shared__ u32 csum[256], cpre[256];
  __shared__ u32 bins[4], prefs[4];
  chunk_sums(h, csum, cpre);
  // virtual indices: 0.03*(n-1)=7864.29 -> {7864,7865}; 0.97*(n-1)=254278.71 -> {254278,254279}
  const u32 ranks[4] = {7864u, 7865u, 254278u, 254279u};
  for (int q = 0; q < 4; ++q)
    find_rank(h, csum, cpre, ranks[q], &bins[q], &prefs[q]);
  __syncthreads();
  if (threadIdx.x == 0) {
    double vlo = (3.0 / 100.0) * (double)(NPIX - 1);
    double vhi = (97.0 / 100.0) * (double)(NPIX - 1);
    double glo = vlo - floor(vlo);
    double ghi = vhi - floor(vhi);
    double l0 = bins[0] / 256.0, l1 = bins[1] / 256.0;
    double h0 = bins[2] / 256.0, h1 = bins[3] / 256.0;
    double lo = l0 + glo * (l1 - l0);
    double hi = h0 + ghi * (h1 - h0);
    lov[ch] = (float)lo;
    invv[ch] = (float)(1.0 / (hi - lo));
  }
}

// ---------------- finalize: (hfc - lo) / (hi - lo) * mask, in place on d_out ----------------

__global__ __launch_bounds__(256) void kfinal(float* __restrict__ out, const float* __restrict__ mask,
                                              const float* __restrict__ lov, const float* __restrict__ invv) {
  size_t i = (size_t)blockIdx.x * 256 + threadIdx.x;
  int ch = (int)(i >> 18);  // 262144 elems per channel
  out[i] = (out[i] - lov[ch]) * invv[ch] * mask[i];
}

// ---------------- launch ----------------

extern "C" void kernel_launch(void* const* d_in, const int* in_sizes, int n_in,
                              void* d_out, int out_size, void* d_ws, size_t ws_size,
                              hipStream_t stream) {
  (void)in_sizes; (void)n_in;
  const float* x = (const float*)d_in[0];
  const float* mask = (const float*)d_in[1];
  const float* fmap = (const float*)d_in[2];
  float* out = (float*)d_out;
  char* ws = (char*)d_ws;

  const size_t HB = (size_t)NCH * 65536 * 4;  // 12.58 MB histogram (reused 3x)
  u32* hist = (u32*)ws;
  float* med = (float*)(ws + HB);
  u32* selhi = (u32*)(ws + HB + 1024);
  u32* pref  = (u32*)(ws + HB + 2048);
  float* lov  = (float*)(ws + HB + 3072);
  float* invv = (float*)(ws + HB + 4096);
  float2* cbuf = (float2*)(ws + HB + 8192);

  // pick channels-per-chunk so the complex buffer fits the workspace
  size_t avail = (ws_size > HB + 8192) ? ws_size - HB - 8192 : 0;
  int cpc = 2;
  const int cands[5] = {16, 12, 8, 6, 4};
  for (int i = 0; i < 5; ++i) {
    if ((size_t)cands[i] * NPIX * sizeof(float2) <= avail) { cpc = cands[i]; break; }
  }

  // median (exact 2-pass radix select on float keys)
  hipMemsetAsync(hist, 0, HB, stream);
  khist_hi<<<NCH * 16, 256, 0, stream>>>(x, hist);
  kscan_hi<<<NCH, 256, 0, stream>>>(hist, selhi, pref);
  hipMemsetAsync(hist, 0, HB, stream);
  khist_lo<<<NCH * 16, 256, 0, stream>>>(x, hist, selhi);
  kscan_lo<<<NCH, 256, 0, stream>>>(hist, selhi, pref, med);

  // FFT2 -> filter -> IFFT2 -> |.| (hfc into d_out), chunked over channels
  for (int ch0 = 0; ch0 < NCH; ch0 += cpc) {
    kfft_row_fwd<<<cpc * 512, 256, 0, stream>>>(x, mask, med, cbuf, ch0);
    kfft_col<1><<<cpc * 64, 256, 0, stream>>>(cbuf, fmap);
    kfft_col<0><<<cpc * 64, 256, 0, stream>>>(cbuf, fmap);
    kfft_row_inv<<<cpc * 512, 256, 0, stream>>>(cbuf, out, ch0);
  }

  // percentiles on temp = trunc(hfc*256)/256 (exact via integer histogram)
  hipMemsetAsync(hist, 0, HB, stream);
  khist_pct<<<NCH * 16, 256, 0, stream>>>(out, hist);
  kpct_scan<<<NCH, 256, 0, stream>>>(hist, lov, invv);

  // normalize * mask, in place
  kfinal<<<(out_size + 255) / 256, 256, 0, stream>>>(out, mask, lov, invv);
}

// Round 2
// 506.038 us; speedup vs baseline: 2.6347x; 2.6347x over previous
//
#include <hip/hip_runtime.h>
#include <math.h>

// FourierButterworthHFCFilter: median-fill -> Butterworth HFC (FFT2) -> percentile norm
// B=16, C=3, H=W=512. 48 channels of 262144 fp32.

#define HN 512
#define WN 512
#define NPIX (HN * WN)   // 262144
#define NCH 48
#define MED_K 131071u    // (n-1)//2

typedef unsigned int u32;

// percentile virtual ranks: 0.03*(n-1)=7864.29 -> {7864,7865}; 0.97*(n-1)=254278.71
__device__ __constant__ u32 PRANKS[4] = {7864u, 7865u, 254278u, 254279u};

__device__ __forceinline__ int rev9(int e) { return (int)(__brev((unsigned)e) >> 23); }

__device__ __forceinline__ u32 f2key(float f) {
  u32 u = __float_as_uint(f);
  return u ^ ((u & 0x80000000u) ? 0xFFFFFFFFu : 0x80000000u);
}
__device__ __forceinline__ float key2f(u32 k) {
  u32 u = (k & 0x80000000u) ? (k ^ 0x80000000u) : ~k;
  return __uint_as_float(u);
}

// generic rank-find over per*256 bins; owning thread writes *out_bin/*out_pref.
// Ends with __syncthreads() so caller may read the outputs immediately after.
__device__ void scan_find(const u32* __restrict__ h, int per, u32 rank,
                          u32* out_bin, u32* out_pref) {
  __shared__ u32 csum[256], cpre[256];
  int t = threadIdx.x;
  u32 s = 0;
  for (int i = 0; i < per; ++i) s += h[t * per + i];
  csum[t] = s;
  __syncthreads();
  if (t == 0) { u32 a = 0; for (int i = 0; i < 256; ++i) { cpre[i] = a; a += csum[i]; } }
  __syncthreads();
  if (cpre[t] <= rank && rank < cpre[t] + csum[t]) {
    u32 acc = cpre[t];
    for (int i = 0; i < per; ++i) {
      u32 c = h[t * per + i];
      if (rank < acc + c) { *out_bin = (u32)(t * per + i); *out_pref = acc; break; }
      acc += c;
    }
  }
  __syncthreads();
}

// ---------------- median: 3-pass LDS radix select (12 + 12 + 8 bits) ----------------

__global__ __launch_bounds__(256) void kmed1(const float4* __restrict__ x4, u32* __restrict__ h1) {
  int ch = blockIdx.x >> 4, s = blockIdx.x & 15;
  __shared__ u32 lh[4096];
  for (int i = threadIdx.x; i < 4096; i += 256) lh[i] = 0;
  __syncthreads();
  const float4* p = x4 + (size_t)ch * (NPIX / 4) + (size_t)s * (NPIX / 64);
  for (int i = threadIdx.x; i < NPIX / 64; i += 256) {
    float4 v = p[i];
    atomicAdd(&lh[f2key(v.x) >> 20], 1u);
    atomicAdd(&lh[f2key(v.y) >> 20], 1u);
    atomicAdd(&lh[f2key(v.z) >> 20], 1u);
    atomicAdd(&lh[f2key(v.w) >> 20], 1u);
  }
  __syncthreads();
  u32* h = h1 + (size_t)ch * 4096;
  for (int i = threadIdx.x; i < 4096; i += 256) { u32 c = lh[i]; if (c) atomicAdd(&h[i], c); }
}

__global__ __launch_bounds__(256) void kscan1(const u32* __restrict__ h1, u32* sel1, u32* pref1) {
  __shared__ u32 b, p;
  scan_find(h1 + (size_t)blockIdx.x * 4096, 16, MED_K, &b, &p);
  if (threadIdx.x == 0) { sel1[blockIdx.x] = b; pref1[blockIdx.x] = p; }
}

__global__ __launch_bounds__(256) void kmed2(const float4* __restrict__ x4, u32* __restrict__ h2,
                                             const u32* __restrict__ sel1) {
  int ch = blockIdx.x >> 4, s = blockIdx.x & 15;
  u32 sh = sel1[ch];
  __shared__ u32 lh[4096];
  for (int i = threadIdx.x; i < 4096; i += 256) lh[i] = 0;
  __syncthreads();
  const float4* p = x4 + (size_t)ch * (NPIX / 4) + (size_t)s * (NPIX / 64);
  for (int i = threadIdx.x; i < NPIX / 64; i += 256) {
    float4 v = p[i];
    u32 k;
    k = f2key(v.x); if ((k >> 20) == sh) atomicAdd(&lh[(k >> 8) & 0xFFFu], 1u);
    k = f2key(v.y); if ((k >> 20) == sh) atomicAdd(&lh[(k >> 8) & 0xFFFu], 1u);
    k = f2key(v.z); if ((k >> 20) == sh) atomicAdd(&lh[(k >> 8) & 0xFFFu], 1u);
    k = f2key(v.w); if ((k >> 20) == sh) atomicAdd(&lh[(k >> 8) & 0xFFFu], 1u);
  }
  __syncthreads();
  u32* h = h2 + (size_t)ch * 4096;
  for (int i = threadIdx.x; i < 4096; i += 256) { u32 c = lh[i]; if (c) atomicAdd(&h[i], c); }
}

__global__ __launch_bounds__(256) void kscan2(const u32* __restrict__ h2, const u32* __restrict__ pref1,
                                              u32* sel2, u32* pref2) {
  __shared__ u32 b, p;
  scan_find(h2 + (size_t)blockIdx.x * 4096, 16, MED_K - pref1[blockIdx.x], &b, &p);
  if (threadIdx.x == 0) { sel2[blockIdx.x] = b; pref2[blockIdx.x] = p; }
}

__global__ __launch_bounds__(256) void kmed3(const float4* __restrict__ x4, u32* __restrict__ h3,
                                             const u32* __restrict__ sel1, const u32* __restrict__ sel2) {
  int ch = blockIdx.x >> 4, s = blockIdx.x & 15;
  u32 pre = (sel1[ch] << 12) | sel2[ch];   // bits 31:8
  __shared__ u32 lh[256];
  lh[threadIdx.x] = 0;
  __syncthreads();
  const float4* p = x4 + (size_t)ch * (NPIX / 4) + (size_t)s * (NPIX / 64);
  for (int i = threadIdx.x; i < NPIX / 64; i += 256) {
    float4 v = p[i];
    u32 k;
    k = f2key(v.x); if ((k >> 8) == pre) atomicAdd(&lh[k & 0xFFu], 1u);
    k = f2key(v.y); if ((k >> 8) == pre) atomicAdd(&lh[k & 0xFFu], 1u);
    k = f2key(v.z); if ((k >> 8) == pre) atomicAdd(&lh[k & 0xFFu], 1u);
    k = f2key(v.w); if ((k >> 8) == pre) atomicAdd(&lh[k & 0xFFu], 1u);
  }
  __syncthreads();
  u32 c = lh[threadIdx.x];
  if (c) atomicAdd(&h3[(size_t)ch * 256 + threadIdx.x], c);
}

__global__ __launch_bounds__(256) void kscan3(const u32* __restrict__ h3, const u32* __restrict__ sel1,
                                              const u32* __restrict__ sel2, const u32* __restrict__ pref1,
                                              const u32* __restrict__ pref2, float* med) {
  int ch = blockIdx.x;
  __shared__ u32 b, p;
  scan_find(h3 + (size_t)ch * 256, 1, MED_K - pref1[ch] - pref2[ch], &b, &p);
  if (threadIdx.x == 0) {
    u32 key = (sel1[ch] << 20) | (sel2[ch] << 8) | b;
    med[ch] = key2f(key) + 0.2f;   // median_padding adds 0.2
  }
}

// ---------------- FFT: DIF forward / DIT inverse (no bit-reversal passes) ----------------

__device__ __forceinline__ void fft512_dif(float2* a, int t) {
  #pragma unroll
  for (int ls = 9; ls >= 1; --ls) {
    const int half = 1 << (ls - 1);
    int p = t & (half - 1);
    int g = t >> (ls - 1);
    int i0 = (g << ls) | p;
    int i1 = i0 + half;
    float ang = -6.283185307179586f * (float)p / (float)(1 << ls);
    float sn, cs; __sincosf(ang, &sn, &cs);
    float2 u = a[i0], v = a[i1];
    a[i0] = make_float2(u.x + v.x, u.y + v.y);
    float dx = u.x - v.x, dy = u.y - v.y;
    a[i1] = make_float2(dx * cs - dy * sn, dx * sn + dy * cs);
    __syncthreads();
  }
}

__device__ __forceinline__ void fft512_dit_inv(float2* a, int t) {
  #pragma unroll
  for (int ls = 1; ls <= 9; ++ls) {
    const int half = 1 << (ls - 1);
    int p = t & (half - 1);
    int g = t >> (ls - 1);
    int i0 = (g << ls) | p;
    int i1 = i0 + half;
    float ang = 6.283185307179586f * (float)p / (float)(1 << ls);
    float sn, cs; __sincosf(ang, &sn, &cs);
    float2 u = a[i0], v = a[i1];
    float vx = v.x * cs - v.y * sn, vy = v.x * sn + v.y * cs;
    a[i0] = make_float2(u.x + vx, u.y + vy);
    a[i1] = make_float2(u.x - vx, u.y - vy);
    __syncthreads();
  }
}

// permute + prescale the filter: fmp[c*HN + h] = fmap[rev9(h)*WN + rev9(c)] / NPIX
__global__ __launch_bounds__(256) void kperm(const float* __restrict__ fmap, float* __restrict__ fmp) {
  int c = blockIdx.x;
  for (int e = threadIdx.x; e < HN; e += 256)
    fmp[(size_t)c * HN + e] = fmap[(size_t)rev9(e) * WN + rev9(c)] * (1.0f / (float)NPIX);
}

// forward row FFT; builds xp = mask*x + (1-mask)*med on the fly. Natural in, bit-rev out.
__global__ __launch_bounds__(256) void krow_fwd(const float2* __restrict__ x2, const float2* __restrict__ m2,
                                                const float* __restrict__ med, float2* __restrict__ cbuf, int ch0) {
  int lch = blockIdx.x >> 9, row = blockIdx.x & 511, gch = ch0 + lch;
  __shared__ float2 lds[512];
  int t = threadIdx.x;
  float mv = med[gch];
  size_t gb = ((size_t)gch * NPIX + (size_t)row * WN) >> 1;  // float2 units
  float2 xv = x2[gb + t], mm = m2[gb + t];
  lds[2 * t]     = make_float2(mm.x * xv.x + (1.0f - mm.x) * mv, 0.0f);
  lds[2 * t + 1] = make_float2(mm.y * xv.y + (1.0f - mm.y) * mv, 0.0f);
  __syncthreads();
  fft512_dif(lds, t);
  float4* cb4 = (float4*)(cbuf + (size_t)lch * NPIX + (size_t)row * WN);
  float2 a = lds[2 * t], b = lds[2 * t + 1];
  cb4[t] = make_float4(a.x, a.y, b.x, b.y);
}

// fused column pass: fwd DIF + filter + inv DIT, 8 columns per block
__global__ __launch_bounds__(256) void kcol(float2* __restrict__ cbuf, const float* __restrict__ fmp) {
  int lch = blockIdx.x >> 6;
  int c0 = (blockIdx.x & 63) << 3;
  __shared__ float2 lds[8][512];
  int t = threadIdx.x;
  size_t base = (size_t)lch * NPIX + c0;
  #pragma unroll
  for (int i = 0; i < 8; ++i) {
    int g = i * 256 + t;
    int h = g >> 2, cc = (g & 3) << 1;
    float4 v = *(const float4*)(cbuf + base + (size_t)h * WN + cc);
    lds[cc][h]     = make_float2(v.x, v.y);
    lds[cc + 1][h] = make_float2(v.z, v.w);
  }
  __syncthreads();
  // forward DIF over h
  #pragma unroll
  for (int ls = 9; ls >= 1; --ls) {
    const int half = 1 << (ls - 1);
    int p = t & (half - 1);
    int g = t >> (ls - 1);
    int i0 = (g << ls) | p;
    int i1 = i0 + half;
    float ang = -6.283185307179586f * (float)p / (float)(1 << ls);
    float sn, cs; __sincosf(ang, &sn, &cs);
    #pragma unroll
    for (int c = 0; c < 8; ++c) {
      float2 u = lds[c][i0], v = lds[c][i1];
      lds[c][i0] = make_float2(u.x + v.x, u.y + v.y);
      float dx = u.x - v.x, dy = u.y - v.y;
      lds[c][i1] = make_float2(dx * cs - dy * sn, dx * sn + dy * cs);
    }
    __syncthreads();
  }
  // filter multiply (data at (physical h, physical col) = freq (rev9(h), rev9(col)); fmp pre-permuted)
  #pragma unroll
  for (int i = 0; i < 16; ++i) {
    int idx = i * 256 + t;
    int c = idx >> 9, h = idx & 511;
    float f = fmp[(size_t)(c0 + c) * HN + h];
    float2 v = lds[c][h];
    lds[c][h] = make_float2(v.x * f, v.y * f);
  }
  __syncthreads();
  // inverse DIT over h
  #pragma unroll
  for (int ls = 1; ls <= 9; ++ls) {
    const int half = 1 << (ls - 1);
    int p = t & (half - 1);
    int g = t >> (ls - 1);
    int i0 = (g << ls) | p;
    int i1 = i0 + half;
    float ang = 6.283185307179586f * (float)p / (float)(1 << ls);
    float sn, cs; __sincosf(ang, &sn, &cs);
    #pragma unroll
    for (int c = 0; c < 8; ++c) {
      float2 u = lds[c][i0], v = lds[c][i1];
      float vx = v.x * cs - v.y * sn, vy = v.x * sn + v.y * cs;
      lds[c][i0] = make_float2(u.x + vx, u.y + vy);
      lds[c][i1] = make_float2(u.x - vx, u.y - vy);
    }
    __syncthreads();
  }
  #pragma unroll
  for (int i = 0; i < 8; ++i) {
    int g = i * 256 + t;
    int h = g >> 2, cc = (g & 3) << 1;
    float2 a = lds[cc][h], b = lds[cc + 1][h];
    *(float4*)(cbuf + base + (size_t)h * WN + cc) = make_float4(a.x, a.y, b.x, b.y);
  }
}

// inverse row FFT + |.| -> out; fused coarse percentile histogram (bin>>8)
__global__ __launch_bounds__(256) void krow_inv(const float2* __restrict__ cbuf, float* __restrict__ out,
                                                u32* __restrict__ hc, int ch0) {
  int lch = blockIdx.x >> 9, row = blockIdx.x & 511, gch = ch0 + lch;
  __shared__ float2 lds[512];
  __shared__ u32 lh[256];
  int t = threadIdx.x;
  lh[t] = 0;
  ((float4*)lds)[t] = ((const float4*)(cbuf + (size_t)lch * NPIX + (size_t)row * WN))[t];
  __syncthreads();
  fft512_dit_inv(lds, t);
  float2 a = lds[2 * t], b = lds[2 * t + 1];
  float h0 = sqrtf(a.x * a.x + a.y * a.y);
  float h1 = sqrtf(b.x * b.x + b.y * b.y);
  ((float2*)(out + (size_t)gch * NPIX + (size_t)row * WN))[t] = make_float2(h0, h1);
  atomicAdd(&lh[((u32)fminf(h0 * 256.0f, 65535.0f)) >> 8], 1u);
  atomicAdd(&lh[((u32)fminf(h1 * 256.0f, 65535.0f)) >> 8], 1u);
  __syncthreads();
  u32 c = lh[t];
  if (c) atomicAdd(&hc[(size_t)gch * 256 + t], c);
}

// ---------------- percentile fine passes ----------------

__global__ __launch_bounds__(256) void kpcts1(const u32* __restrict__ hc, u32* selc, u32* prefc) {
  int ch = blockIdx.x;
  __shared__ u32 b, p;
  for (int q = 0; q < 4; ++q) {
    scan_find(hc + (size_t)ch * 256, 1, PRANKS[q], &b, &p);
    if (threadIdx.x == 0) { selc[ch * 4 + q] = b; prefc[ch * 4 + q] = p; }
    __syncthreads();
  }
}

__global__ __launch_bounds__(256) void kpctf(const float4* __restrict__ out4, u32* __restrict__ hf,
                                             const u32* __restrict__ selc) {
  int ch = blockIdx.x >> 3, s = blockIdx.x & 7;
  u32 t0 = selc[ch * 4 + 0], t1 = selc[ch * 4 + 1], t2 = selc[ch * 4 + 2], t3 = selc[ch * 4 + 3];
  __shared__ u32 lh[1024];
  for (int i = threadIdx.x; i < 1024; i += 256) lh[i] = 0;
  __syncthreads();
  const float4* p = out4 + (size_t)ch * (NPIX / 4) + (size_t)s * (NPIX / 32);
  for (int i = threadIdx.x; i < NPIX / 32; i += 256) {
    float4 v = p[i];
    float vv[4] = {v.x, v.y, v.z, v.w};
    #pragma unroll
    for (int j = 0; j < 4; ++j) {
      u32 bin = (u32)fminf(vv[j] * 256.0f, 65535.0f);
      u32 cb = bin >> 8, fb = bin & 255u;
      if (cb == t0) atomicAdd(&lh[0 * 256 + fb], 1u);
      if (cb == t1) atomicAdd(&lh[1 * 256 + fb], 1u);
      if (cb == t2) atomicAdd(&lh[2 * 256 + fb], 1u);
      if (cb == t3) atomicAdd(&lh[3 * 256 + fb], 1u);
    }
  }
  __syncthreads();
  for (int i = threadIdx.x; i < 1024; i += 256) {
    u32 c = lh[i];
    if (c) atomicAdd(&hf[(size_t)ch * 1024 + i], c);
  }
}

__global__ __launch_bounds__(256) void kpcts2(const u32* __restrict__ hf, const u32* __restrict__ selc,
                                              const u32* __restrict__ prefc, float* lov, float* invv) {
  int ch = blockIdx.x;
  __shared__ u32 b, p;
  __shared__ u32 bins[4];
  for (int q = 0; q < 4; ++q) {
    scan_find(hf + (size_t)ch * 1024 + q * 256, 1, PRANKS[q] - prefc[ch * 4 + q], &b, &p);
    if (threadIdx.x == 0) bins[q] = (selc[ch * 4 + q] << 8) | b;
    __syncthreads();
  }
  if (threadIdx.x == 0) {
    double vlo = 0.03 * (double)(NPIX - 1);
    double vhi = 0.97 * (double)(NPIX - 1);
    double glo = vlo - floor(vlo);
    double ghi = vhi - floor(vhi);
    double l0 = bins[0] / 256.0, l1 = bins[1] / 256.0;
    double h0 = bins[2] / 256.0, h1 = bins[3] / 256.0;
    double lo = l0 + glo * (l1 - l0);
    double hi = h0 + ghi * (h1 - h0);
    lov[ch] = (float)lo;
    invv[ch] = (float)(1.0 / (hi - lo));
  }
}

// ---------------- finalize ----------------

__global__ __launch_bounds__(256) void kfinal(float4* __restrict__ o4, const float4* __restrict__ m4,
                                              const float* __restrict__ lov, const float* __restrict__ invv) {
  size_t i = (size_t)blockIdx.x * 256 + threadIdx.x;
  int ch = (int)(i >> 16);  // 65536 float4 per channel
  float lo = lov[ch], iv = invv[ch];
  float4 o = o4[i], m = m4[i];
  o.x = (o.x - lo) * iv * m.x;
  o.y = (o.y - lo) * iv * m.y;
  o.z = (o.z - lo) * iv * m.z;
  o.w = (o.w - lo) * iv * m.w;
  o4[i] = o;
}

// ---------------- launch ----------------

extern "C" void kernel_launch(void* const* d_in, const int* in_sizes, int n_in,
                              void* d_out, int out_size, void* d_ws, size_t ws_size,
                              hipStream_t stream) {
  (void)in_sizes; (void)n_in;
  const float* x = (const float*)d_in[0];
  const float* mask = (const float*)d_in[1];
  const float* fmap = (const float*)d_in[2];
  float* out = (float*)d_out;
  char* ws = (char*)d_ws;

  // ---- workspace layout (bytes) ----
  size_t off = 0;
  u32* h1 = (u32*)(ws + off); off += (size_t)NCH * 4096 * 4;   // 786432
  u32* h2 = (u32*)(ws + off); off += (size_t)NCH * 4096 * 4;   // 786432
  u32* h3 = (u32*)(ws + off); off += (size_t)NCH * 256 * 4;    // 49152
  u32* hc = (u32*)(ws + off); off += (size_t)NCH * 256 * 4;    // 49152
  u32* hf = (u32*)(ws + off); off += (size_t)NCH * 1024 * 4;   // 196608
  const size_t HIST_BYTES = off;                               // 1867776 — zeroed each call
  u32* sel1  = (u32*)(ws + off); off += NCH * 4;
  u32* pref1 = (u32*)(ws + off); off += NCH * 4;
  u32* sel2  = (u32*)(ws + off); off += NCH * 4;
  u32* pref2 = (u32*)(ws + off); off += NCH * 4;
  u32* selc  = (u32*)(ws + off); off += NCH * 16;
  u32* prefc = (u32*)(ws + off); off += NCH * 16;
  float* med  = (float*)(ws + off); off += NCH * 4;
  float* lov  = (float*)(ws + off); off += NCH * 4;
  float* invv = (float*)(ws + off); off += NCH * 4;
  off = (off + 4095) & ~(size_t)4095;
  float* fmp = (float*)(ws + off); off += (size_t)NPIX * 4;    // permuted+prescaled filter
  off = (off + 255) & ~(size_t)255;
  float2* cbuf = (float2*)(ws + off);

  size_t avail = (ws_size > off) ? ws_size - off : 0;
  int cpc = 1;
  const int cands[7] = {16, 12, 8, 6, 4, 2, 1};
  for (int i = 0; i < 7; ++i) {
    if ((size_t)cands[i] * NPIX * sizeof(float2) <= avail) { cpc = cands[i]; break; }
  }

  hipMemsetAsync(ws, 0, HIST_BYTES, stream);
  kperm<<<WN, 256, 0, stream>>>(fmap, fmp);

  // median: exact 3-pass LDS radix select
  kmed1<<<NCH * 16, 256, 0, stream>>>((const float4*)x, h1);
  kscan1<<<NCH, 256, 0, stream>>>(h1, sel1, pref1);
  kmed2<<<NCH * 16, 256, 0, stream>>>((const float4*)x, h2, sel1);
  kscan2<<<NCH, 256, 0, stream>>>(h2, pref1, sel2, pref2);
  kmed3<<<NCH * 16, 256, 0, stream>>>((const float4*)x, h3, sel1, sel2);
  kscan3<<<NCH, 256, 0, stream>>>(h3, sel1, sel2, pref1, pref2, med);

  // FFT2 -> filter -> IFFT2 -> |.| (into d_out) + fused coarse percentile hist
  for (int ch0 = 0; ch0 < NCH; ch0 += cpc) {
    int cc = (NCH - ch0 < cpc) ? (NCH - ch0) : cpc;
    krow_fwd<<<cc * 512, 256, 0, stream>>>((const float2*)x, (const float2*)mask, med, cbuf, ch0);
    kcol<<<cc * 64, 256, 0, stream>>>(cbuf, fmp);
    krow_inv<<<cc * 512, 256, 0, stream>>>(cbuf, out, hc, ch0);
  }

  // percentile: coarse scan -> fine hist -> final scan
  kpcts1<<<NCH, 256, 0, stream>>>(hc, selc, prefc);
  kpctf<<<NCH * 8, 256, 0, stream>>>((const float4*)out, hf, selc);
  kpcts2<<<NCH, 256, 0, stream>>>(hf, selc, prefc, lov, invv);

  // normalize * mask, in place, vectorized
  kfinal<<<(NCH * NPIX / 4) / 256, 256, 0, stream>>>((float4*)out, (const float4*)mask, lov, invv);
}

// Round 4
// 372.246 us; speedup vs baseline: 3.5816x; 1.3594x over previous
//
#include <hip/hip_runtime.h>
#include <math.h>

// FourierButterworthHFCFilter: median-fill -> Butterworth HFC (FFT2) -> percentile norm
// B=16, C=3, H=W=512. 48 channels of 262144 fp32.
// Radix-8 FFT (512 = 8^3): DIF forward (natural->digit-reversed), DIT inverse
// (digit-reversed->natural). Filter applied in digit-reversed order via pre-permuted map.

#define HN 512
#define WN 512
#define NPIX (HN * WN)   // 262144
#define NCH 48
#define MED_K 131071u    // (n-1)//2
#define TWOPI 6.283185307179586f

typedef unsigned int u32;

// percentile virtual ranks: 0.03*(n-1)=7864.29 -> {7864,7865}; 0.97*(n-1)=254278.71
__device__ __constant__ u32 PRANKS[4] = {7864u, 7865u, 254278u, 254279u};

// base-8 digit reversal of 9-bit index
__device__ __forceinline__ int rev8_9(int i) { return ((i & 7) << 6) | (i & 56) | (i >> 6); }

// padded LDS index: insert one float2 gap every 8 elements (injective, max 574 < 576)
#define LPAD 576
__device__ __forceinline__ int padi(int i) { return i + (i >> 3); }

__device__ __forceinline__ u32 f2key(float f) {
  u32 u = __float_as_uint(f);
  return u ^ ((u & 0x80000000u) ? 0xFFFFFFFFu : 0x80000000u);
}
__device__ __forceinline__ float key2f(u32 k) {
  u32 u = (k & 0x80000000u) ? (k ^ 0x80000000u) : ~k;
  return __uint_as_float(u);
}

__device__ __forceinline__ float2 cadd(float2 a, float2 b) { return make_float2(a.x + b.x, a.y + b.y); }
__device__ __forceinline__ float2 csub(float2 a, float2 b) { return make_float2(a.x - b.x, a.y - b.y); }
__device__ __forceinline__ float2 cmul(float2 a, float2 b) {
  return make_float2(a.x * b.x - a.y * b.y, a.x * b.y + a.y * b.x);
}

// 8-point DFT in registers. INV=false: w8 = e^{-i pi/4}; INV=true: conjugate.
template <bool INV>
__device__ __forceinline__ void dft8(float2* r) {
  const float S2 = 0.70710678118654752f;
  float2 e0, e1, e2, e3, o0, o1, o2, o3;
  {
    float2 t0 = cadd(r[0], r[4]), t1 = csub(r[0], r[4]);
    float2 t2 = cadd(r[2], r[6]), t3 = csub(r[2], r[6]);
    e0 = cadd(t0, t2); e2 = csub(t0, t2);
    if (!INV) { e1 = make_float2(t1.x + t3.y, t1.y - t3.x); e3 = make_float2(t1.x - t3.y, t1.y + t3.x); }
    else      { e1 = make_float2(t1.x - t3.y, t1.y + t3.x); e3 = make_float2(t1.x + t3.y, t1.y - t3.x); }
  }
  {
    float2 t0 = cadd(r[1], r[5]), t1 = csub(r[1], r[5]);
    float2 t2 = cadd(r[3], r[7]), t3 = csub(r[3], r[7]);
    o0 = cadd(t0, t2); o2 = csub(t0, t2);
    if (!INV) { o1 = make_float2(t1.x + t3.y, t1.y - t3.x); o3 = make_float2(t1.x - t3.y, t1.y + t3.x); }
    else      { o1 = make_float2(t1.x - t3.y, t1.y + t3.x); o3 = make_float2(t1.x + t3.y, t1.y - t3.x); }
  }
  float2 w1o, w2o, w3o;
  if (!INV) {
    w1o = make_float2(S2 * (o1.x + o1.y), S2 * (o1.y - o1.x));   // *(1-i)s
    w2o = make_float2(o2.y, -o2.x);                              // *(-i)
    w3o = make_float2(S2 * (o3.y - o3.x), -S2 * (o3.x + o3.y));  // *-(1+i)s
  } else {
    w1o = make_float2(S2 * (o1.x - o1.y), S2 * (o1.x + o1.y));   // *(1+i)s
    w2o = make_float2(-o2.y, o2.x);                              // *(+i)
    w3o = make_float2(-S2 * (o3.x + o3.y), S2 * (o3.x - o3.y));  // *(-1+i)s
  }
  r[0] = cadd(e0, o0); r[4] = csub(e0, o0);
  r[1] = cadd(e1, w1o); r[5] = csub(e1, w1o);
  r[2] = cadd(e2, w2o); r[6] = csub(e2, w2o);
  r[3] = cadd(e3, w3o); r[7] = csub(e3, w3o);
}

// multiply r[j] *= w^j with w = e^{i*ang} (post-twiddle for DIF, pre-twiddle for DIT)
__device__ __forceinline__ void twid(float2* r, float ang) {
  float sn, cs;
  __sincosf(ang, &sn, &cs);
  float2 w = make_float2(cs, sn);
  float2 wj = w;
  r[1] = cmul(r[1], wj);
  #pragma unroll
  for (int j = 2; j < 8; ++j) { wj = cmul(wj, w); r[j] = cmul(r[j], wj); }
}

// generic rank-find over per*256 bins; owning thread writes outputs; ends with barrier.
__device__ void scan_find(const u32* __restrict__ h, int per, u32 rank,
                          u32* out_bin, u32* out_pref) {
  __shared__ u32 csum[256], cpre[256];
  int t = threadIdx.x;
  u32 s = 0;
  for (int i = 0; i < per; ++i) s += h[t * per + i];
  csum[t] = s;
  __syncthreads();
  if (t == 0) { u32 a = 0; for (int i = 0; i < 256; ++i) { cpre[i] = a; a += csum[i]; } }
  __syncthreads();
  if (cpre[t] <= rank && rank < cpre[t] + csum[t]) {
    u32 acc = cpre[t];
    for (int i = 0; i < per; ++i) {
      u32 c = h[t * per + i];
      if (rank < acc + c) { *out_bin = (u32)(t * per + i); *out_pref = acc; break; }
      acc += c;
    }
  }
  __syncthreads();
}

// ---------------- median: 3-pass LDS radix select (12 + 12 + 8 bits) ----------------

__global__ __launch_bounds__(256) void kmed1(const float4* __restrict__ x4, u32* __restrict__ h1) {
  int ch = blockIdx.x >> 4, s = blockIdx.x & 15;
  __shared__ u32 lh[4096];
  for (int i = threadIdx.x; i < 4096; i += 256) lh[i] = 0;
  __syncthreads();
  const float4* p = x4 + (size_t)ch * (NPIX / 4) + (size_t)s * (NPIX / 64);
  for (int i = threadIdx.x; i < NPIX / 64; i += 256) {
    float4 v = p[i];
    atomicAdd(&lh[f2key(v.x) >> 20], 1u);
    atomicAdd(&lh[f2key(v.y) >> 20], 1u);
    atomicAdd(&lh[f2key(v.z) >> 20], 1u);
    atomicAdd(&lh[f2key(v.w) >> 20], 1u);
  }
  __syncthreads();
  u32* h = h1 + (size_t)ch * 4096;
  for (int i = threadIdx.x; i < 4096; i += 256) { u32 c = lh[i]; if (c) atomicAdd(&h[i], c); }
}

__global__ __launch_bounds__(256) void kscan1(const u32* __restrict__ h1, u32* sel1, u32* pref1) {
  __shared__ u32 b, p;
  scan_find(h1 + (size_t)blockIdx.x * 4096, 16, MED_K, &b, &p);
  if (threadIdx.x == 0) { sel1[blockIdx.x] = b; pref1[blockIdx.x] = p; }
}

__global__ __launch_bounds__(256) void kmed2(const float4* __restrict__ x4, u32* __restrict__ h2,
                                             const u32* __restrict__ sel1) {
  int ch = blockIdx.x >> 4, s = blockIdx.x & 15;
  u32 sh = sel1[ch];
  __shared__ u32 lh[4096];
  for (int i = threadIdx.x; i < 4096; i += 256) lh[i] = 0;
  __syncthreads();
  const float4* p = x4 + (size_t)ch * (NPIX / 4) + (size_t)s * (NPIX / 64);
  for (int i = threadIdx.x; i < NPIX / 64; i += 256) {
    float4 v = p[i];
    u32 k;
    k = f2key(v.x); if ((k >> 20) == sh) atomicAdd(&lh[(k >> 8) & 0xFFFu], 1u);
    k = f2key(v.y); if ((k >> 20) == sh) atomicAdd(&lh[(k >> 8) & 0xFFFu], 1u);
    k = f2key(v.z); if ((k >> 20) == sh) atomicAdd(&lh[(k >> 8) & 0xFFFu], 1u);
    k = f2key(v.w); if ((k >> 20) == sh) atomicAdd(&lh[(k >> 8) & 0xFFFu], 1u);
  }
  __syncthreads();
  u32* h = h2 + (size_t)ch * 4096;
  for (int i = threadIdx.x; i < 4096; i += 256) { u32 c = lh[i]; if (c) atomicAdd(&h[i], c); }
}

__global__ __launch_bounds__(256) void kscan2(const u32* __restrict__ h2, const u32* __restrict__ pref1,
                                              u32* sel2, u32* pref2) {
  __shared__ u32 b, p;
  scan_find(h2 + (size_t)blockIdx.x * 4096, 16, MED_K - pref1[blockIdx.x], &b, &p);
  if (threadIdx.x == 0) { sel2[blockIdx.x] = b; pref2[blockIdx.x] = p; }
}

__global__ __launch_bounds__(256) void kmed3(const float4* __restrict__ x4, u32* __restrict__ h3,
                                             const u32* __restrict__ sel1, const u32* __restrict__ sel2) {
  int ch = blockIdx.x >> 4, s = blockIdx.x & 15;
  u32 pre = (sel1[ch] << 12) | sel2[ch];   // bits 31:8
  __shared__ u32 lh[256];
  lh[threadIdx.x] = 0;
  __syncthreads();
  const float4* p = x4 + (size_t)ch * (NPIX / 4) + (size_t)s * (NPIX / 64);
  for (int i = threadIdx.x; i < NPIX / 64; i += 256) {
    float4 v = p[i];
    u32 k;
    k = f2key(v.x); if ((k >> 8) == pre) atomicAdd(&lh[k & 0xFFu], 1u);
    k = f2key(v.y); if ((k >> 8) == pre) atomicAdd(&lh[k & 0xFFu], 1u);
    k = f2key(v.z); if ((k >> 8) == pre) atomicAdd(&lh[k & 0xFFu], 1u);
    k = f2key(v.w); if ((k >> 8) == pre) atomicAdd(&lh[k & 0xFFu], 1u);
  }
  __syncthreads();
  u32 c = lh[threadIdx.x];
  if (c) atomicAdd(&h3[(size_t)ch * 256 + threadIdx.x], c);
}

__global__ __launch_bounds__(256) void kscan3(const u32* __restrict__ h3, const u32* __restrict__ sel1,
                                              const u32* __restrict__ sel2, const u32* __restrict__ pref1,
                                              const u32* __restrict__ pref2, float* med) {
  int ch = blockIdx.x;
  __shared__ u32 b, p;
  scan_find(h3 + (size_t)ch * 256, 1, MED_K - pref1[ch] - pref2[ch], &b, &p);
  if (threadIdx.x == 0) {
    u32 key = (sel1[ch] << 20) | (sel2[ch] << 8) | b;
    med[ch] = key2f(key) + 0.2f;   // median_padding adds 0.2
  }
}

// ---------------- filter permute: fmp[c*HN + h] = fmap[rev8(h)][rev8(c)] / NPIX ----------------

__global__ __launch_bounds__(256) void kperm(const float* __restrict__ fmap, float* __restrict__ fmp) {
  int c = blockIdx.x;
  for (int e = threadIdx.x; e < HN; e += 256)
    fmp[(size_t)c * HN + e] = fmap[(size_t)rev8_9(e) * WN + rev8_9(c)] * (1.0f / (float)NPIX);
}

// ---------------- row forward FFT (radix-8, 1 wave = 1 row, 4 rows/block) ----------------

__global__ __launch_bounds__(256) void krow_fwd(const float* __restrict__ x, const float* __restrict__ mask,
                                                const float* __restrict__ med, float2* __restrict__ cbuf, int ch0) {
  int lch = blockIdx.x >> 7, rb = blockIdx.x & 127;
  int gch = ch0 + lch;
  int lane = threadIdx.x & 63, r = threadIdx.x >> 6;
  int row = rb * 4 + r;
  __shared__ float2 lds[4][LPAD];
  float2* L = lds[r];
  float mv = med[gch];
  const float* xr = x + (size_t)gch * NPIX + (size_t)row * WN;
  const float* mr = mask + (size_t)gch * NPIX + (size_t)row * WN;
  float2 rg[8];
  // stage A operands are exactly elements {lane + 64m} -> load straight into regs (coalesced)
  #pragma unroll
  for (int m = 0; m < 8; ++m) {
    float xv = xr[lane + 64 * m], mm = mr[lane + 64 * m];
    rg[m] = make_float2(mm * xv + (1.0f - mm) * mv, 0.0f);
  }
  dft8<false>(rg);
  twid(rg, (float)lane * (-TWOPI / 512.0f));
  int pb = lane + (lane >> 3);
  #pragma unroll
  for (int j = 0; j < 8; ++j) L[pb + 72 * j] = rg[j];
  __syncthreads();
  // stage B: elements 64b + n0 + 8m, phys = 72b + n0 + 9m
  int n0 = lane & 7;
  int pb2 = 72 * (lane >> 3) + n0;
  #pragma unroll
  for (int m = 0; m < 8; ++m) rg[m] = L[pb2 + 9 * m];
  dft8<false>(rg);
  twid(rg, (float)n0 * (-TWOPI / 64.0f));
  #pragma unroll
  for (int j = 0; j < 8; ++j) L[pb2 + 9 * j] = rg[j];
  __syncthreads();
  // stage C: elements 8b + m, phys = 9*lane + m (no twiddle)
  int pc = 9 * lane;
  #pragma unroll
  for (int m = 0; m < 8; ++m) rg[m] = L[pc + m];
  dft8<false>(rg);
  #pragma unroll
  for (int j = 0; j < 8; ++j) L[pc + j] = rg[j];
  __syncthreads();
  // coalesced store (element pairs are contiguous in padded layout: even index never hits a gap)
  float2* cb = cbuf + (size_t)lch * NPIX + (size_t)row * WN;
  #pragma unroll
  for (int q = 0; q < 4; ++q) {
    int e = 2 * (lane + 64 * q);
    int pe = padi(e);
    float2 a = L[pe], b = L[pe + 1];
    *(float4*)(cb + e) = make_float4(a.x, a.y, b.x, b.y);
  }
}

// ---------------- fused column pass: fwd DIF + filter + inv DIT (8 cols/block, 8 waves) ----------------

__global__ __launch_bounds__(512) void kcol(float2* __restrict__ cbuf, const float* __restrict__ fmp) {
  int lch = blockIdx.x >> 6;
  int c0 = (blockIdx.x & 63) << 3;
  int tid = threadIdx.x;
  int lane = tid & 63, cc = tid >> 6;   // wave cc owns column c0+cc
  __shared__ float2 lds[8][LPAD];
  float2* L = lds[cc];
  size_t base = (size_t)lch * NPIX + c0;
  // coalesced load: per row h, 8 cols = 4 float4 -> 512 rows * 4 = 2048 float4 = 4 iters * 512 thr
  #pragma unroll
  for (int it = 0; it < 4; ++it) {
    int g = it * 512 + tid;
    int h = g >> 2, qq = g & 3;
    float4 v = *(const float4*)(cbuf + base + (size_t)h * WN + 2 * qq);
    int ph = padi(h);
    lds[2 * qq][ph]     = make_float2(v.x, v.y);
    lds[2 * qq + 1][ph] = make_float2(v.z, v.w);
  }
  __syncthreads();
  float2 rg[8];
  int pb = lane + (lane >> 3);
  int n0 = lane & 7;
  int pb2 = 72 * (lane >> 3) + n0;
  int pc = 9 * lane;
  // ---- forward stage A
  #pragma unroll
  for (int m = 0; m < 8; ++m) rg[m] = L[pb + 72 * m];
  dft8<false>(rg);
  twid(rg, (float)lane * (-TWOPI / 512.0f));
  #pragma unroll
  for (int j = 0; j < 8; ++j) L[pb + 72 * j] = rg[j];
  __syncthreads();
  // ---- forward stage B
  #pragma unroll
  for (int m = 0; m < 8; ++m) rg[m] = L[pb2 + 9 * m];
  dft8<false>(rg);
  twid(rg, (float)n0 * (-TWOPI / 64.0f));
  #pragma unroll
  for (int j = 0; j < 8; ++j) L[pb2 + 9 * j] = rg[j];
  __syncthreads();
  // ---- forward stage C + filter + inverse stage C' : all on lane-local positions {8*lane+j}
  #pragma unroll
  for (int m = 0; m < 8; ++m) rg[m] = L[pc + m];
  dft8<false>(rg);
  {
    const float* fp = fmp + (size_t)(c0 + cc) * HN + 8 * lane;
    float4 f0 = *(const float4*)fp, f1 = *(const float4*)(fp + 4);
    rg[0].x *= f0.x; rg[0].y *= f0.x;  rg[1].x *= f0.y; rg[1].y *= f0.y;
    rg[2].x *= f0.z; rg[2].y *= f0.z;  rg[3].x *= f0.w; rg[3].y *= f0.w;
    rg[4].x *= f1.x; rg[4].y *= f1.x;  rg[5].x *= f1.y; rg[5].y *= f1.y;
    rg[6].x *= f1.z; rg[6].y *= f1.z;  rg[7].x *= f1.w; rg[7].y *= f1.w;
  }
  dft8<true>(rg);
  #pragma unroll
  for (int j = 0; j < 8; ++j) L[pc + j] = rg[j];
  __syncthreads();
  // ---- inverse stage B' (pre-twiddle)
  #pragma unroll
  for (int m = 0; m < 8; ++m) rg[m] = L[pb2 + 9 * m];
  twid(rg, (float)n0 * (TWOPI / 64.0f));
  dft8<true>(rg);
  #pragma unroll
  for (int j = 0; j < 8; ++j) L[pb2 + 9 * j] = rg[j];
  __syncthreads();
  // ---- inverse stage A' (pre-twiddle)
  #pragma unroll
  for (int m = 0; m < 8; ++m) rg[m] = L[pb + 72 * m];
  twid(rg, (float)lane * (TWOPI / 512.0f));
  dft8<true>(rg);
  #pragma unroll
  for (int j = 0; j < 8; ++j) L[pb + 72 * j] = rg[j];
  __syncthreads();
  // coalesced store (2048 float4 = 4 iters * 512 thr)
  #pragma unroll
  for (int it = 0; it < 4; ++it) {
    int g = it * 512 + tid;
    int h = g >> 2, qq = g & 3;
    int ph = padi(h);
    float2 a = lds[2 * qq][ph], b = lds[2 * qq + 1][ph];
    *(float4*)(cbuf + base + (size_t)h * WN + 2 * qq) = make_float4(a.x, a.y, b.x, b.y);
  }
}

// ---------------- row inverse FFT + |.| + fused coarse percentile histogram ----------------

__global__ __launch_bounds__(256) void krow_inv(const float2* __restrict__ cbuf, float* __restrict__ out,
                                                u32* __restrict__ hc, int ch0) {
  int lch = blockIdx.x >> 7, rb = blockIdx.x & 127;
  int gch = ch0 + lch;
  int lane = threadIdx.x & 63, r = threadIdx.x >> 6;
  int row = rb * 4 + r;
  __shared__ float2 lds[4][LPAD];
  __shared__ u32 lh[256];
  float2* L = lds[r];
  lh[threadIdx.x] = 0;
  const float2* cb = cbuf + (size_t)lch * NPIX + (size_t)row * WN;
  #pragma unroll
  for (int q = 0; q < 4; ++q) {
    int e = 2 * (lane + 64 * q);
    float4 v = *(const float4*)(cb + e);
    int pe = padi(e);
    L[pe]     = make_float2(v.x, v.y);
    L[pe + 1] = make_float2(v.z, v.w);
  }
  __syncthreads();
  float2 rg[8];
  int pc = 9 * lane;
  // stage C' (no twiddle)
  #pragma unroll
  for (int m = 0; m < 8; ++m) rg[m] = L[pc + m];
  dft8<true>(rg);
  #pragma unroll
  for (int j = 0; j < 8; ++j) L[pc + j] = rg[j];
  __syncthreads();
  // stage B' (pre-twiddle)
  int n0 = lane & 7;
  int pb2 = 72 * (lane >> 3) + n0;
  #pragma unroll
  for (int m = 0; m < 8; ++m) rg[m] = L[pb2 + 9 * m];
  twid(rg, (float)n0 * (TWOPI / 64.0f));
  dft8<true>(rg);
  #pragma unroll
  for (int j = 0; j < 8; ++j) L[pb2 + 9 * j] = rg[j];
  __syncthreads();
  // stage A' (pre-twiddle) -> rg[j] = natural element (lane + 64j): finish in regs
  int pb = lane + (lane >> 3);
  #pragma unroll
  for (int m = 0; m < 8; ++m) rg[m] = L[pb + 72 * m];
  twid(rg, (float)lane * (TWOPI / 512.0f));
  dft8<true>(rg);
  float* orow = out + (size_t)gch * NPIX + (size_t)row * WN;
  #pragma unroll
  for (int j = 0; j < 8; ++j) {
    float mg = sqrtf(rg[j].x * rg[j].x + rg[j].y * rg[j].y);
    orow[lane + 64 * j] = mg;
    u32 bin = (u32)fminf(mg * 256.0f, 65535.0f);
    atomicAdd(&lh[bin >> 8], 1u);
  }
  __syncthreads();
  u32 c = lh[threadIdx.x];
  if (c) atomicAdd(&hc[(size_t)gch * 256 + threadIdx.x], c);
}

// ---------------- percentile fine passes ----------------

__global__ __launch_bounds__(256) void kpcts1(const u32* __restrict__ hc, u32* selc, u32* prefc) {
  int ch = blockIdx.x;
  __shared__ u32 b, p;
  for (int q = 0; q < 4; ++q) {
    scan_find(hc + (size_t)ch * 256, 1, PRANKS[q], &b, &p);
    if (threadIdx.x == 0) { selc[ch * 4 + q] = b; prefc[ch * 4 + q] = p; }
    __syncthreads();
  }
}

__global__ __launch_bounds__(256) void kpctf(const float4* __restrict__ out4, u32* __restrict__ hf,
                                             const u32* __restrict__ selc) {
  int ch = blockIdx.x >> 3, s = blockIdx.x & 7;
  u32 t0 = selc[ch * 4 + 0], t1 = selc[ch * 4 + 1], t2 = selc[ch * 4 + 2], t3 = selc[ch * 4 + 3];
  __shared__ u32 lh[1024];
  for (int i = threadIdx.x; i < 1024; i += 256) lh[i] = 0;
  __syncthreads();
  const float4* p = out4 + (size_t)ch * (NPIX / 4) + (size_t)s * (NPIX / 32);
  for (int i = threadIdx.x; i < NPIX / 32; i += 256) {
    float4 v = p[i];
    float vv[4] = {v.x, v.y, v.z, v.w};
    #pragma unroll
    for (int j = 0; j < 4; ++j) {
      u32 bin = (u32)fminf(vv[j] * 256.0f, 65535.0f);
      u32 cb = bin >> 8, fb = bin & 255u;
      if (cb == t0) atomicAdd(&lh[0 * 256 + fb], 1u);
      if (cb == t1) atomicAdd(&lh[1 * 256 + fb], 1u);
      if (cb == t2) atomicAdd(&lh[2 * 256 + fb], 1u);
      if (cb == t3) atomicAdd(&lh[3 * 256 + fb], 1u);
    }
  }
  __syncthreads();
  for (int i = threadIdx.x; i < 1024; i += 256) {
    u32 c = lh[i];
    if (c) atomicAdd(&hf[(size_t)ch * 1024 + i], c);
  }
}

__global__ __launch_bounds__(256) void kpcts2(const u32* __restrict__ hf, const u32* __restrict__ selc,
                                              const u32* __restrict__ prefc, float* lov, float* invv) {
  int ch = blockIdx.x;
  __shared__ u32 b, p;
  __shared__ u32 bins[4];
  for (int q = 0; q < 4; ++q) {
    scan_find(hf + (size_t)ch * 1024 + q * 256, 1, PRANKS[q] - prefc[ch * 4 + q], &b, &p);
    if (threadIdx.x == 0) bins[q] = (selc[ch * 4 + q] << 8) | b;
    __syncthreads();
  }
  if (threadIdx.x == 0) {
    double vlo = 0.03 * (double)(NPIX - 1);
    double vhi = 0.97 * (double)(NPIX - 1);
    double glo = vlo - floor(vlo);
    double ghi = vhi - floor(vhi);
    double l0 = bins[0] / 256.0, l1 = bins[1] / 256.0;
    double h0 = bins[2] / 256.0, h1 = bins[3] / 256.0;
    double lo = l0 + glo * (l1 - l0);
    double hi = h0 + ghi * (h1 - h0);
    lov[ch] = (float)lo;
    invv[ch] = (float)(1.0 / (hi - lo));
  }
}

// ---------------- finalize ----------------

__global__ __launch_bounds__(256) void kfinal(float4* __restrict__ o4, const float4* __restrict__ m4,
                                              const float* __restrict__ lov, const float* __restrict__ invv) {
  size_t i = (size_t)blockIdx.x * 256 + threadIdx.x;
  int ch = (int)(i >> 16);  // 65536 float4 per channel
  float lo = lov[ch], iv = invv[ch];
  float4 o = o4[i], m = m4[i];
  o.x = (o.x - lo) * iv * m.x;
  o.y = (o.y - lo) * iv * m.y;
  o.z = (o.z - lo) * iv * m.z;
  o.w = (o.w - lo) * iv * m.w;
  o4[i] = o;
}

// ---------------- launch ----------------

extern "C" void kernel_launch(void* const* d_in, const int* in_sizes, int n_in,
                              void* d_out, int out_size, void* d_ws, size_t ws_size,
                              hipStream_t stream) {
  (void)in_sizes; (void)n_in; (void)out_size;
  const float* x = (const float*)d_in[0];
  const float* mask = (const float*)d_in[1];
  const float* fmap = (const float*)d_in[2];
  float* out = (float*)d_out;
  char* ws = (char*)d_ws;

  // ---- workspace layout (bytes) ----
  size_t off = 0;
  u32* h1 = (u32*)(ws + off); off += (size_t)NCH * 4096 * 4;
  u32* h2 = (u32*)(ws + off); off += (size_t)NCH * 4096 * 4;
  u32* h3 = (u32*)(ws + off); off += (size_t)NCH * 256 * 4;
  u32* hc = (u32*)(ws + off); off += (size_t)NCH * 256 * 4;
  u32* hf = (u32*)(ws + off); off += (size_t)NCH * 1024 * 4;
  const size_t HIST_BYTES = off;
  u32* sel1  = (u32*)(ws + off); off += NCH * 4;
  u32* pref1 = (u32*)(ws + off); off += NCH * 4;
  u32* sel2  = (u32*)(ws + off); off += NCH * 4;
  u32* pref2 = (u32*)(ws + off); off += NCH * 4;
  u32* selc  = (u32*)(ws + off); off += NCH * 16;
  u32* prefc = (u32*)(ws + off); off += NCH * 16;
  float* med  = (float*)(ws + off); off += NCH * 4;
  float* lov  = (float*)(ws + off); off += NCH * 4;
  float* invv = (float*)(ws + off); off += NCH * 4;
  off = (off + 4095) & ~(size_t)4095;
  float* fmp = (float*)(ws + off); off += (size_t)NPIX * 4;   // permuted+prescaled filter
  off = (off + 255) & ~(size_t)255;
  float2* cbuf = (float2*)(ws + off);

  size_t avail = (ws_size > off) ? ws_size - off : 0;
  int cpc = 1;
  const int cands[8] = {48, 24, 16, 12, 8, 4, 2, 1};
  for (int i = 0; i < 8; ++i) {
    if ((size_t)cands[i] * NPIX * sizeof(float2) <= avail) { cpc = cands[i]; break; }
  }

  hipMemsetAsync(ws, 0, HIST_BYTES, stream);
  kperm<<<WN, 256, 0, stream>>>(fmap, fmp);

  // median: exact 3-pass LDS radix select
  kmed1<<<NCH * 16, 256, 0, stream>>>((const float4*)x, h1);
  kscan1<<<NCH, 256, 0, stream>>>(h1, sel1, pref1);
  kmed2<<<NCH * 16, 256, 0, stream>>>((const float4*)x, h2, sel1);
  kscan2<<<NCH, 256, 0, stream>>>(h2, pref1, sel2, pref2);
  kmed3<<<NCH * 16, 256, 0, stream>>>((const float4*)x, h3, sel1, sel2);
  kscan3<<<NCH, 256, 0, stream>>>(h3, sel1, sel2, pref1, pref2, med);

  // FFT2 -> filter -> IFFT2 -> |.| (into d_out) + fused coarse percentile hist
  for (int ch0 = 0; ch0 < NCH; ch0 += cpc) {
    int cc = (NCH - ch0 < cpc) ? (NCH - ch0) : cpc;
    krow_fwd<<<cc * 128, 256, 0, stream>>>(x, mask, med, cbuf, ch0);
    kcol<<<cc * 64, 512, 0, stream>>>(cbuf, fmp);
    krow_inv<<<cc * 128, 256, 0, stream>>>(cbuf, out, hc, ch0);
  }

  // percentile: coarse scan -> fine hist -> final scan
  kpcts1<<<NCH, 256, 0, stream>>>(hc, selc, prefc);
  kpctf<<<NCH * 8, 256, 0, stream>>>((const float4*)out, hf, selc);
  kpcts2<<<NCH, 256, 0, stream>>>(hf, selc, prefc, lov, invv);

  // normalize * mask, in place, vectorized
  kfinal<<<(NCH * NPIX / 4) / 256, 256, 0, stream>>>((float4*)out, (const float4*)mask, lov, invv);
}

// Round 6
// 366.815 us; speedup vs baseline: 3.6346x; 1.0148x over previous
//
#include <hip/hip_runtime.h>
#include <math.h>

// FourierButterworthHFCFilter: median-fill -> Butterworth HFC (FFT2) -> percentile norm
// B=16, C=3, H=W=512. 48 channels of 262144 fp32.
// Radix-8 FFT (512 = 8^3), DIF fwd / DIT inv, XOR-swizzled LDS (no padding),
// wave-synchronous stages (no block barriers), ballot-aggregated histograms.

#define HN 512
#define WN 512
#define NPIX (HN * WN)   // 262144
#define NCH 48
#define MED_K 131071u    // (n-1)//2
#define TWOPI 6.283185307179586f

typedef unsigned int u32;
typedef float f4v __attribute__((ext_vector_type(4)));   // for nontemporal store

// percentile virtual ranks: 0.03*(n-1)=7864.29 -> {7864,7865}; 0.97*(n-1)=254278.71
__device__ __constant__ u32 PRANKS[4] = {7864u, 7865u, 254278u, 254279u};

// base-8 digit reversal of 9-bit index
__device__ __forceinline__ int rev8_9(int i) { return ((i & 7) << 6) | (i & 56) | (i >> 6); }

// XOR-swizzled LDS index: bijective, puts stage A/B/C access patterns at the
// 4-lane-per-bank-pair floor for b64 accesses (no padding needed).
__device__ __forceinline__ int swz(int e) { return e ^ ((e >> 4) & 0xF); }

#define WB() __builtin_amdgcn_wave_barrier()

__device__ __forceinline__ u32 f2key(float f) {
  u32 u = __float_as_uint(f);
  return u ^ ((u & 0x80000000u) ? 0xFFFFFFFFu : 0x80000000u);
}
__device__ __forceinline__ float key2f(u32 k) {
  u32 u = (k & 0x80000000u) ? (k ^ 0x80000000u) : ~k;
  return __uint_as_float(u);
}

__device__ __forceinline__ float2 cadd(float2 a, float2 b) { return make_float2(a.x + b.x, a.y + b.y); }
__device__ __forceinline__ float2 csub(float2 a, float2 b) { return make_float2(a.x - b.x, a.y - b.y); }
__device__ __forceinline__ float2 cmul(float2 a, float2 b) {
  return make_float2(a.x * b.x - a.y * b.y, a.x * b.y + a.y * b.x);
}

// 8-point DFT in registers. INV=false: w8 = e^{-i pi/4}; INV=true: conjugate.
template <bool INV>
__device__ __forceinline__ void dft8(float2* r) {
  const float S2 = 0.70710678118654752f;
  float2 e0, e1, e2, e3, o0, o1, o2, o3;
  {
    float2 t0 = cadd(r[0], r[4]), t1 = csub(r[0], r[4]);
    float2 t2 = cadd(r[2], r[6]), t3 = csub(r[2], r[6]);
    e0 = cadd(t0, t2); e2 = csub(t0, t2);
    if (!INV) { e1 = make_float2(t1.x + t3.y, t1.y - t3.x); e3 = make_float2(t1.x - t3.y, t1.y + t3.x); }
    else      { e1 = make_float2(t1.x - t3.y, t1.y + t3.x); e3 = make_float2(t1.x + t3.y, t1.y - t3.x); }
  }
  {
    float2 t0 = cadd(r[1], r[5]), t1 = csub(r[1], r[5]);
    float2 t2 = cadd(r[3], r[7]), t3 = csub(r[3], r[7]);
    o0 = cadd(t0, t2); o2 = csub(t0, t2);
    if (!INV) { o1 = make_float2(t1.x + t3.y, t1.y - t3.x); o3 = make_float2(t1.x - t3.y, t1.y + t3.x); }
    else      { o1 = make_float2(t1.x - t3.y, t1.y + t3.x); o3 = make_float2(t1.x + t3.y, t1.y - t3.x); }
  }
  float2 w1o, w2o, w3o;
  if (!INV) {
    w1o = make_float2(S2 * (o1.x + o1.y), S2 * (o1.y - o1.x));   // *(1-i)s
    w2o = make_float2(o2.y, -o2.x);                              // *(-i)
    w3o = make_float2(S2 * (o3.y - o3.x), -S2 * (o3.x + o3.y));  // *-(1+i)s
  } else {
    w1o = make_float2(S2 * (o1.x - o1.y), S2 * (o1.x + o1.y));   // *(1+i)s
    w2o = make_float2(-o2.y, o2.x);                              // *(+i)
    w3o = make_float2(-S2 * (o3.x + o3.y), S2 * (o3.x - o3.y));  // *(-1+i)s
  }
  r[0] = cadd(e0, o0); r[4] = csub(e0, o0);
  r[1] = cadd(e1, w1o); r[5] = csub(e1, w1o);
  r[2] = cadd(e2, w2o); r[6] = csub(e2, w2o);
  r[3] = cadd(e3, w3o); r[7] = csub(e3, w3o);
}

// multiply r[j] *= w^j with w = e^{i*ang}
__device__ __forceinline__ void twid(float2* r, float ang) {
  float sn, cs;
  __sincosf(ang, &sn, &cs);
  float2 w = make_float2(cs, sn);
  float2 wj = w;
  r[1] = cmul(r[1], wj);
  #pragma unroll
  for (int j = 2; j < 8; ++j) { wj = cmul(wj, w); r[j] = cmul(r[j], wj); }
}

// generic rank-find over per*256 bins; owning thread writes outputs; ends with barrier.
__device__ void scan_find(const u32* __restrict__ h, int per, u32 rank,
                          u32* out_bin, u32* out_pref) {
  __shared__ u32 csum[256], cpre[256];
  int t = threadIdx.x;
  u32 s = 0;
  for (int i = 0; i < per; ++i) s += h[t * per + i];
  csum[t] = s;
  __syncthreads();
  if (t == 0) { u32 a = 0; for (int i = 0; i < 256; ++i) { cpre[i] = a; a += csum[i]; } }
  __syncthreads();
  if (cpre[t] <= rank && rank < cpre[t] + csum[t]) {
    u32 acc = cpre[t];
    for (int i = 0; i < per; ++i) {
      u32 c = h[t * per + i];
      if (rank < acc + c) { *out_bin = (u32)(t * per + i); *out_pref = acc; break; }
      acc += c;
    }
  }
  __syncthreads();
}

// ---------------- median: 3-pass LDS radix select (12 + 12 + 8 bits) ----------------

__global__ __launch_bounds__(256) void kmed1(const float4* __restrict__ x4, u32* __restrict__ h1) {
  int ch = blockIdx.x >> 4, s = blockIdx.x & 15;
  __shared__ u32 lh[4096];
  for (int i = threadIdx.x; i < 4096; i += 256) lh[i] = 0;
  __syncthreads();
  const float4* p = x4 + (size_t)ch * (NPIX / 4) + (size_t)s * (NPIX / 64);
  for (int i = threadIdx.x; i < NPIX / 64; i += 256) {
    float4 v = p[i];
    atomicAdd(&lh[f2key(v.x) >> 20], 1u);
    atomicAdd(&lh[f2key(v.y) >> 20], 1u);
    atomicAdd(&lh[f2key(v.z) >> 20], 1u);
    atomicAdd(&lh[f2key(v.w) >> 20], 1u);
  }
  __syncthreads();
  u32* h = h1 + (size_t)ch * 4096;
  for (int i = threadIdx.x; i < 4096; i += 256) { u32 c = lh[i]; if (c) atomicAdd(&h[i], c); }
}

__global__ __launch_bounds__(256) void kscan1(const u32* __restrict__ h1, u32* sel1, u32* pref1) {
  __shared__ u32 b, p;
  scan_find(h1 + (size_t)blockIdx.x * 4096, 16, MED_K, &b, &p);
  if (threadIdx.x == 0) { sel1[blockIdx.x] = b; pref1[blockIdx.x] = p; }
}

__global__ __launch_bounds__(256) void kmed2(const float4* __restrict__ x4, u32* __restrict__ h2,
                                             const u32* __restrict__ sel1) {
  int ch = blockIdx.x >> 4, s = blockIdx.x & 15;
  u32 sh = sel1[ch];
  __shared__ u32 lh[4096];
  for (int i = threadIdx.x; i < 4096; i += 256) lh[i] = 0;
  __syncthreads();
  const float4* p = x4 + (size_t)ch * (NPIX / 4) + (size_t)s * (NPIX / 64);
  for (int i = threadIdx.x; i < NPIX / 64; i += 256) {
    float4 v = p[i];
    u32 k;
    k = f2key(v.x); if ((k >> 20) == sh) atomicAdd(&lh[(k >> 8) & 0xFFFu], 1u);
    k = f2key(v.y); if ((k >> 20) == sh) atomicAdd(&lh[(k >> 8) & 0xFFFu], 1u);
    k = f2key(v.z); if ((k >> 20) == sh) atomicAdd(&lh[(k >> 8) & 0xFFFu], 1u);
    k = f2key(v.w); if ((k >> 20) == sh) atomicAdd(&lh[(k >> 8) & 0xFFFu], 1u);
  }
  __syncthreads();
  u32* h = h2 + (size_t)ch * 4096;
  for (int i = threadIdx.x; i < 4096; i += 256) { u32 c = lh[i]; if (c) atomicAdd(&h[i], c); }
}

__global__ __launch_bounds__(256) void kscan2(const u32* __restrict__ h2, const u32* __restrict__ pref1,
                                              u32* sel2, u32* pref2) {
  __shared__ u32 b, p;
  scan_find(h2 + (size_t)blockIdx.x * 4096, 16, MED_K - pref1[blockIdx.x], &b, &p);
  if (threadIdx.x == 0) { sel2[blockIdx.x] = b; pref2[blockIdx.x] = p; }
}

__global__ __launch_bounds__(256) void kmed3(const float4* __restrict__ x4, u32* __restrict__ h3,
                                             const u32* __restrict__ sel1, const u32* __restrict__ sel2) {
  int ch = blockIdx.x >> 4, s = blockIdx.x & 15;
  u32 pre = (sel1[ch] << 12) | sel2[ch];   // bits 31:8
  __shared__ u32 lh[256];
  lh[threadIdx.x] = 0;
  __syncthreads();
  const float4* p = x4 + (size_t)ch * (NPIX / 4) + (size_t)s * (NPIX / 64);
  for (int i = threadIdx.x; i < NPIX / 64; i += 256) {
    float4 v = p[i];
    u32 k;
    k = f2key(v.x); if ((k >> 8) == pre) atomicAdd(&lh[k & 0xFFu], 1u);
    k = f2key(v.y); if ((k >> 8) == pre) atomicAdd(&lh[k & 0xFFu], 1u);
    k = f2key(v.z); if ((k >> 8) == pre) atomicAdd(&lh[k & 0xFFu], 1u);
    k = f2key(v.w); if ((k >> 8) == pre) atomicAdd(&lh[k & 0xFFu], 1u);
  }
  __syncthreads();
  u32 c = lh[threadIdx.x];
  if (c) atomicAdd(&h3[(size_t)ch * 256 + threadIdx.x], c);
}

__global__ __launch_bounds__(256) void kscan3(const u32* __restrict__ h3, const u32* __restrict__ sel1,
                                              const u32* __restrict__ sel2, const u32* __restrict__ pref1,
                                              const u32* __restrict__ pref2, float* med) {
  int ch = blockIdx.x;
  __shared__ u32 b, p;
  scan_find(h3 + (size_t)ch * 256, 1, MED_K - pref1[ch] - pref2[ch], &b, &p);
  if (threadIdx.x == 0) {
    u32 key = (sel1[ch] << 20) | (sel2[ch] << 8) | b;
    med[ch] = key2f(key) + 0.2f;   // median_padding adds 0.2
  }
}

// ---------------- filter permute: fmp[c*HN + h] = fmap[rev8(h)][rev8(c)] / NPIX ----------------

__global__ __launch_bounds__(256) void kperm(const float* __restrict__ fmap, float* __restrict__ fmp) {
  int c = blockIdx.x;
  for (int e = threadIdx.x; e < HN; e += 256)
    fmp[(size_t)c * HN + e] = fmap[(size_t)rev8_9(e) * WN + rev8_9(c)] * (1.0f / (float)NPIX);
}

// ---------------- row forward FFT (radix-8, 1 wave = 1 row, 4 rows/block, barrier-free) ----------------

__global__ __launch_bounds__(256) void krow_fwd(const float* __restrict__ x, const float* __restrict__ mask,
                                                const float* __restrict__ med, float2* __restrict__ cbuf, int ch0) {
  int lch = blockIdx.x >> 7, rb = blockIdx.x & 127;
  int gch = ch0 + lch;
  int lane = threadIdx.x & 63, r = threadIdx.x >> 6;
  int row = rb * 4 + r;
  __shared__ float2 lds[4][512];
  float2* L = lds[r];
  float mv = med[gch];
  const float* xr = x + (size_t)gch * NPIX + (size_t)row * WN;
  const float* mr = mask + (size_t)gch * NPIX + (size_t)row * WN;
  float2 rg[8];
  // stage A operands = elements {lane + 64m}: load straight into regs (coalesced)
  #pragma unroll
  for (int m = 0; m < 8; ++m) {
    float xv = xr[lane + 64 * m], mm = mr[lane + 64 * m];
    rg[m] = make_float2(mm * xv + (1.0f - mm) * mv, 0.0f);
  }
  dft8<false>(rg);
  twid(rg, (float)lane * (-TWOPI / 512.0f));
  #pragma unroll
  for (int j = 0; j < 8; ++j) L[swz(lane + 64 * j)] = rg[j];
  WB();
  // stage B: elements 64b + n0 + 8m
  int eb = 64 * (lane >> 3) + (lane & 7);
  #pragma unroll
  for (int m = 0; m < 8; ++m) rg[m] = L[swz(eb + 8 * m)];
  dft8<false>(rg);
  twid(rg, (float)(lane & 7) * (-TWOPI / 64.0f));
  #pragma unroll
  for (int j = 0; j < 8; ++j) L[swz(eb + 8 * j)] = rg[j];
  WB();
  // stage C: elements 8*lane + m; swz(8*lane+m) == pcb ^ m
  int pcb = (8 * lane) ^ ((lane >> 1) & 0xF);
  #pragma unroll
  for (int m = 0; m < 8; ++m) rg[m] = L[pcb ^ m];
  dft8<false>(rg);
  #pragma unroll
  for (int j = 0; j < 8; ++j) L[pcb ^ j] = rg[j];
  WB();
  // coalesced store: elem e at swz(e), elem e+1 at swz(e)^1 (e even)
  float2* cb = cbuf + (size_t)lch * NPIX + (size_t)row * WN;
  #pragma unroll
  for (int q = 0; q < 4; ++q) {
    int e = 2 * (lane + 64 * q);
    int s = swz(e);
    float2 a = L[s], b = L[s ^ 1];
    *(float4*)(cb + e) = make_float4(a.x, a.y, b.x, b.y);
  }
}

// ---- fused column pass: fwd DIF + filter + inv DIT (16 cols/block, 16 waves, 64 KiB LDS) ----

__global__ __launch_bounds__(1024, 8) void kcol(float2* __restrict__ cbuf, const float* __restrict__ fmp) {
  int lch = blockIdx.x >> 5;
  int c0 = (blockIdx.x & 31) << 4;
  int tid = threadIdx.x;
  int lane = tid & 63, w = tid >> 6;   // wave w owns column c0+w
  __shared__ float2 lds[16][512];      // exactly 64 KiB
  float2* L = lds[w];
  size_t base = (size_t)lch * NPIX + c0;
  // coalesced load: per row h, 16 cols = 8 float4 (one full 128B line per row)
  #pragma unroll
  for (int it = 0; it < 4; ++it) {
    int g = it * 1024 + tid;
    int h = g >> 3, qq = g & 7;
    float4 v = *(const float4*)(cbuf + base + (size_t)h * WN + 2 * qq);
    int sh = swz(h);
    lds[2 * qq][sh]     = make_float2(v.x, v.y);
    lds[2 * qq + 1][sh] = make_float2(v.z, v.w);
  }
  __syncthreads();
  float2 rg[8];
  int eb = 64 * (lane >> 3) + (lane & 7);
  int pcb = (8 * lane) ^ ((lane >> 1) & 0xF);
  // ---- forward stage A
  #pragma unroll
  for (int m = 0; m < 8; ++m) rg[m] = L[swz(lane + 64 * m)];
  dft8<false>(rg);
  twid(rg, (float)lane * (-TWOPI / 512.0f));
  #pragma unroll
  for (int j = 0; j < 8; ++j) L[swz(lane + 64 * j)] = rg[j];
  WB();
  // ---- forward stage B
  #pragma unroll
  for (int m = 0; m < 8; ++m) rg[m] = L[swz(eb + 8 * m)];
  dft8<false>(rg);
  twid(rg, (float)(lane & 7) * (-TWOPI / 64.0f));
  #pragma unroll
  for (int j = 0; j < 8; ++j) L[swz(eb + 8 * j)] = rg[j];
  WB();
  // ---- forward stage C + filter + inverse stage C' (lane-local positions 8*lane+j)
  #pragma unroll
  for (int m = 0; m < 8; ++m) rg[m] = L[pcb ^ m];
  dft8<false>(rg);
  {
    const float* fp = fmp + (size_t)(c0 + w) * HN + 8 * lane;
    float4 f0 = *(const float4*)fp, f1 = *(const float4*)(fp + 4);
    rg[0].x *= f0.x; rg[0].y *= f0.x;  rg[1].x *= f0.y; rg[1].y *= f0.y;
    rg[2].x *= f0.z; rg[2].y *= f0.z;  rg[3].x *= f0.w; rg[3].y *= f0.w;
    rg[4].x *= f1.x; rg[4].y *= f1.x;  rg[5].x *= f1.y; rg[5].y *= f1.y;
    rg[6].x *= f1.z; rg[6].y *= f1.z;  rg[7].x *= f1.w; rg[7].y *= f1.w;
  }
  dft8<true>(rg);
  #pragma unroll
  for (int j = 0; j < 8; ++j) L[pcb ^ j] = rg[j];
  WB();
  // ---- inverse stage B' (pre-twiddle)
  #pragma unroll
  for (int m = 0; m < 8; ++m) rg[m] = L[swz(eb + 8 * m)];
  twid(rg, (float)(lane & 7) * (TWOPI / 64.0f));
  dft8<true>(rg);
  #pragma unroll
  for (int j = 0; j < 8; ++j) L[swz(eb + 8 * j)] = rg[j];
  WB();
  // ---- inverse stage A' (pre-twiddle)
  #pragma unroll
  for (int m = 0; m < 8; ++m) rg[m] = L[swz(lane + 64 * m)];
  twid(rg, (float)lane * (TWOPI / 512.0f));
  dft8<true>(rg);
  #pragma unroll
  for (int j = 0; j < 8; ++j) L[swz(lane + 64 * j)] = rg[j];
  __syncthreads();
  // coalesced store
  #pragma unroll
  for (int it = 0; it < 4; ++it) {
    int g = it * 1024 + tid;
    int h = g >> 3, qq = g & 7;
    int sh = swz(h);
    float2 a = lds[2 * qq][sh], b = lds[2 * qq + 1][sh];
    *(float4*)(cbuf + base + (size_t)h * WN + 2 * qq) = make_float4(a.x, a.y, b.x, b.y);
  }
}

// ---- row inverse FFT + |.| + ballot-aggregated coarse percentile histogram (barrier-free) ----

__global__ __launch_bounds__(256) void krow_inv(const float2* __restrict__ cbuf, float* __restrict__ out,
                                                u32* __restrict__ hc, int ch0) {
  int lch = blockIdx.x >> 7, rb = blockIdx.x & 127;
  int gch = ch0 + lch;
  int lane = threadIdx.x & 63, r = threadIdx.x >> 6;
  int row = rb * 4 + r;
  __shared__ float2 lds[4][512];
  __shared__ u32 lh[4][256];   // wave-private histograms
  float2* L = lds[r];
  u32* H = lh[r];
  #pragma unroll
  for (int i = 0; i < 4; ++i) H[lane + 64 * i] = 0;
  const float2* cb = cbuf + (size_t)lch * NPIX + (size_t)row * WN;
  #pragma unroll
  for (int q = 0; q < 4; ++q) {
    int e = 2 * (lane + 64 * q);
    float4 v = *(const float4*)(cb + e);
    int s = swz(e);
    L[s]     = make_float2(v.x, v.y);
    L[s ^ 1] = make_float2(v.z, v.w);
  }
  WB();
  float2 rg[8];
  // stage C' (no twiddle)
  int pcb = (8 * lane) ^ ((lane >> 1) & 0xF);
  #pragma unroll
  for (int m = 0; m < 8; ++m) rg[m] = L[pcb ^ m];
  dft8<true>(rg);
  #pragma unroll
  for (int j = 0; j < 8; ++j) L[pcb ^ j] = rg[j];
  WB();
  // stage B' (pre-twiddle)
  int eb = 64 * (lane >> 3) + (lane & 7);
  #pragma unroll
  for (int m = 0; m < 8; ++m) rg[m] = L[swz(eb + 8 * m)];
  twid(rg, (float)(lane & 7) * (TWOPI / 64.0f));
  dft8<true>(rg);
  #pragma unroll
  for (int j = 0; j < 8; ++j) L[swz(eb + 8 * j)] = rg[j];
  WB();
  // stage A' (pre-twiddle) -> rg[j] = natural element (lane + 64j): finish in regs
  #pragma unroll
  for (int m = 0; m < 8; ++m) rg[m] = L[swz(lane + 64 * m)];
  twid(rg, (float)lane * (TWOPI / 512.0f));
  dft8<true>(rg);
  float* orow = out + (size_t)gch * NPIX + (size_t)row * WN;
  u32 binv[8];
  #pragma unroll
  for (int j = 0; j < 8; ++j) {
    float mg = sqrtf(rg[j].x * rg[j].x + rg[j].y * rg[j].y);
    orow[lane + 64 * j] = mg;
    binv[j] = ((u32)fminf(mg * 256.0f, 65535.0f)) >> 8;
  }
  // wave-aggregated histogram: one atomic per distinct coarse bin per wave (~4 expected)
  #pragma unroll 1
  for (int j = 0; j < 8; ++j) {
    u32 bin = binv[j];
    unsigned long long todo = __ballot(1);
    while (todo) {
      int src = (int)(__ffsll((unsigned long long)todo) - 1);
      u32 b = (u32)__shfl((int)bin, src);
      unsigned long long mt = __ballot(bin == b);
      if (lane == src) atomicAdd(&H[b], (u32)__popcll(mt));
      todo &= ~mt;
    }
  }
  // merge wave-private histogram (same wave, in-order: no barrier needed)
  #pragma unroll
  for (int i = 0; i < 4; ++i) {
    u32 c = H[lane + 64 * i];
    if (c) atomicAdd(&hc[(size_t)gch * 256 + lane + 64 * i], c);
  }
}

// ---------------- percentile fine passes ----------------

__global__ __launch_bounds__(256) void kpcts1(const u32* __restrict__ hc, u32* selc, u32* prefc) {
  int ch = blockIdx.x;
  __shared__ u32 b, p;
  for (int q = 0; q < 4; ++q) {
    scan_find(hc + (size_t)ch * 256, 1, PRANKS[q], &b, &p);
    if (threadIdx.x == 0) { selc[ch * 4 + q] = b; prefc[ch * 4 + q] = p; }
    __syncthreads();
  }
}

__global__ __launch_bounds__(256) void kpctf(const float4* __restrict__ out4, u32* __restrict__ hf,
                                             const u32* __restrict__ selc) {
  int ch = blockIdx.x >> 3, s = blockIdx.x & 7;
  u32 t0 = selc[ch * 4 + 0], t1 = selc[ch * 4 + 1], t2 = selc[ch * 4 + 2], t3 = selc[ch * 4 + 3];
  __shared__ u32 lh[1024];
  for (int i = threadIdx.x; i < 1024; i += 256) lh[i] = 0;
  __syncthreads();
  const float4* p = out4 + (size_t)ch * (NPIX / 4) + (size_t)s * (NPIX / 32);
  for (int i = threadIdx.x; i < NPIX / 32; i += 256) {
    float4 v = p[i];
    float vv[4] = {v.x, v.y, v.z, v.w};
    #pragma unroll
    for (int j = 0; j < 4; ++j) {
      u32 bin = (u32)fminf(vv[j] * 256.0f, 65535.0f);
      u32 cb = bin >> 8, fb = bin & 255u;
      if (cb == t0) atomicAdd(&lh[0 * 256 + fb], 1u);
      if (cb == t1) atomicAdd(&lh[1 * 256 + fb], 1u);
      if (cb == t2) atomicAdd(&lh[2 * 256 + fb], 1u);
      if (cb == t3) atomicAdd(&lh[3 * 256 + fb], 1u);
    }
  }
  __syncthreads();
  for (int i = threadIdx.x; i < 1024; i += 256) {
    u32 c = lh[i];
    if (c) atomicAdd(&hf[(size_t)ch * 1024 + i], c);
  }
}

__global__ __launch_bounds__(256) void kpcts2(const u32* __restrict__ hf, const u32* __restrict__ selc,
                                              const u32* __restrict__ prefc, float* lov, float* invv) {
  int ch = blockIdx.x;
  __shared__ u32 b, p;
  __shared__ u32 bins[4];
  for (int q = 0; q < 4; ++q) {
    scan_find(hf + (size_t)ch * 1024 + q * 256, 1, PRANKS[q] - prefc[ch * 4 + q], &b, &p);
    if (threadIdx.x == 0) bins[q] = (selc[ch * 4 + q] << 8) | b;
    __syncthreads();
  }
  if (threadIdx.x == 0) {
    double vlo = 0.03 * (double)(NPIX - 1);
    double vhi = 0.97 * (double)(NPIX - 1);
    double glo = vlo - floor(vlo);
    double ghi = vhi - floor(vhi);
    double l0 = bins[0] / 256.0, l1 = bins[1] / 256.0;
    double h0 = bins[2] / 256.0, h1 = bins[3] / 256.0;
    double lo = l0 + glo * (l1 - l0);
    double hi = h0 + ghi * (h1 - h0);
    lov[ch] = (float)lo;
    invv[ch] = (float)(1.0 / (hi - lo));
  }
}

// ---------------- finalize ----------------

__global__ __launch_bounds__(256) void kfinal(float4* __restrict__ o4, const float4* __restrict__ m4,
                                              const float* __restrict__ lov, const float* __restrict__ invv) {
  size_t i = (size_t)blockIdx.x * 256 + threadIdx.x;
  int ch = (int)(i >> 16);  // 65536 float4 per channel
  float lo = lov[ch], iv = invv[ch];
  float4 o = o4[i], m = m4[i];
  f4v res;
  res.x = (o.x - lo) * iv * m.x;
  res.y = (o.y - lo) * iv * m.y;
  res.z = (o.z - lo) * iv * m.z;
  res.w = (o.w - lo) * iv * m.w;
  __builtin_nontemporal_store(res, (f4v*)&o4[i]);
}

// ---------------- launch ----------------

extern "C" void kernel_launch(void* const* d_in, const int* in_sizes, int n_in,
                              void* d_out, int out_size, void* d_ws, size_t ws_size,
                              hipStream_t stream) {
  (void)in_sizes; (void)n_in; (void)out_size;
  const float* x = (const float*)d_in[0];
  const float* mask = (const float*)d_in[1];
  const float* fmap = (const float*)d_in[2];
  float* out = (float*)d_out;
  char* ws = (char*)d_ws;

  // ---- workspace layout (bytes) ----
  size_t off = 0;
  u32* h1 = (u32*)(ws + off); off += (size_t)NCH * 4096 * 4;
  u32* h2 = (u32*)(ws + off); off += (size_t)NCH * 4096 * 4;
  u32* h3 = (u32*)(ws + off); off += (size_t)NCH * 256 * 4;
  u32* hc = (u32*)(ws + off); off += (size_t)NCH * 256 * 4;
  u32* hf = (u32*)(ws + off); off += (size_t)NCH * 1024 * 4;
  const size_t HIST_BYTES = off;
  u32* sel1  = (u32*)(ws + off); off += NCH * 4;
  u32* pref1 = (u32*)(ws + off); off += NCH * 4;
  u32* sel2  = (u32*)(ws + off); off += NCH * 4;
  u32* pref2 = (u32*)(ws + off); off += NCH * 4;
  u32* selc  = (u32*)(ws + off); off += NCH * 16;
  u32* prefc = (u32*)(ws + off); off += NCH * 16;
  float* med  = (float*)(ws + off); off += NCH * 4;
  float* lov  = (float*)(ws + off); off += NCH * 4;
  float* invv = (float*)(ws + off); off += NCH * 4;
  off = (off + 4095) & ~(size_t)4095;
  float* fmp = (float*)(ws + off); off += (size_t)NPIX * 4;   // permuted+prescaled filter
  off = (off + 255) & ~(size_t)255;
  float2* cbuf = (float2*)(ws + off);

  size_t avail = (ws_size > off) ? ws_size - off : 0;
  int cpc = 1;
  const int cands[8] = {48, 24, 16, 12, 8, 4, 2, 1};
  for (int i = 0; i < 8; ++i) {
    if ((size_t)cands[i] * NPIX * sizeof(float2) <= avail) { cpc = cands[i]; break; }
  }

  (void)hipMemsetAsync(ws, 0, HIST_BYTES, stream);
  kperm<<<WN, 256, 0, stream>>>(fmap, fmp);

  // median: exact 3-pass LDS radix select
  kmed1<<<NCH * 16, 256, 0, stream>>>((const float4*)x, h1);
  kscan1<<<NCH, 256, 0, stream>>>(h1, sel1, pref1);
  kmed2<<<NCH * 16, 256, 0, stream>>>((const float4*)x, h2, sel1);
  kscan2<<<NCH, 256, 0, stream>>>(h2, pref1, sel2, pref2);
  kmed3<<<NCH * 16, 256, 0, stream>>>((const float4*)x, h3, sel1, sel2);
  kscan3<<<NCH, 256, 0, stream>>>(h3, sel1, sel2, pref1, pref2, med);

  // FFT2 -> filter -> IFFT2 -> |.| (into d_out) + fused coarse percentile hist
  for (int ch0 = 0; ch0 < NCH; ch0 += cpc) {
    int cc = (NCH - ch0 < cpc) ? (NCH - ch0) : cpc;
    krow_fwd<<<cc * 128, 256, 0, stream>>>(x, mask, med, cbuf, ch0);
    kcol<<<cc * 32, 1024, 0, stream>>>(cbuf, fmp);
    krow_inv<<<cc * 128, 256, 0, stream>>>(cbuf, out, hc, ch0);
  }

  // percentile: coarse scan -> fine hist -> final scan
  kpcts1<<<NCH, 256, 0, stream>>>(hc, selc, prefc);
  kpctf<<<NCH * 8, 256, 0, stream>>>((const float4*)out, hf, selc);
  kpcts2<<<NCH, 256, 0, stream>>>(hf, selc, prefc, lov, invv);

  // normalize * mask, in place, vectorized
  kfinal<<<(NCH * NPIX / 4) / 256, 256, 0, stream>>>((float4*)out, (const float4*)mask, lov, invv);
}